// Round 1
// baseline (143.175 us; speedup 1.0000x reference)
//
#include <hip/hip_runtime.h>
#include <math.h>

// Problem constants
#define NQ 10
#define DIM 1024          // 2^10
#define NPTS 64
#define DFEAT 10
#define NLAYERS 5
#define REGS 16           // DIM / 64 amplitudes per lane

// ---------------------------------------------------------------------------
// Kernel 1: simulate psi_i = U(x_i)|0> for each data point i (one wave/block).
// State layout: amplitude index idx = (r<<6) | lane, lane in [0,64), r in [0,16).
// Bits 0..5 of idx live in the lane index (cross-lane via shfl_xor);
// bits 6..9 live in the register index r (in-register butterflies).
// ---------------------------------------------------------------------------
__global__ __launch_bounds__(64) void state_kernel(
    const float* __restrict__ data,     // (64,10)
    const float* __restrict__ params,   // (5,2,10)
    float2* __restrict__ psi)           // (64,1024)
{
    const int i    = blockIdx.x;
    const int lane = threadIdx.x;

    // rz angle for qubit q is x[(start + 9 - q) % 10]; all starts are
    // multiples of 10, so theta_q = x[9-q] in every layer.
    float xr[NQ];
    {
        const float* x = data + i * DFEAT;
        for (int q = 0; q < NQ; ++q) xr[q] = x[9 - q];
    }

    float re[REGS], im[REGS];
    for (int r = 0; r < REGS; ++r) { re[r] = 0.f; im[r] = 0.f; }
    if (lane == 0) re[0] = 1.f;   // |0>

    const float is2 = 0.70710678118654752440f;

    for (int layer = 0; layer < NLAYERS; ++layer) {
        const float* ry = params + layer * 2 * NQ;       // bp[0]
        const float* rg = params + layer * 2 * NQ + NQ;  // bp[1]

        // ---- H on all qubits ----
        for (int q = 0; q < 6; ++q) {
            const int mask = 1 << q;
            for (int r = 0; r < REGS; ++r) {
                float pr = __shfl_xor(re[r], mask, 64);
                float pi = __shfl_xor(im[r], mask, 64);
                if (lane & mask) { re[r] = (pr - re[r]) * is2; im[r] = (pi - im[r]) * is2; }
                else             { re[r] = (re[r] + pr) * is2; im[r] = (im[r] + pi) * is2; }
            }
        }
        for (int q = 6; q < NQ; ++q) {
            const int m = 1 << (q - 6);
            for (int r = 0; r < REGS; ++r) {
                if (!(r & m)) {
                    const int r1 = r | m;
                    float a0r = re[r], a0i = im[r], a1r = re[r1], a1i = im[r1];
                    re[r]  = (a0r + a1r) * is2;  im[r]  = (a0i + a1i) * is2;
                    re[r1] = (a0r - a1r) * is2;  im[r1] = (a0i - a1i) * is2;
                }
            }
        }

        // ---- rz diagonal: phase = sum_q (b_q - 0.5) * xr[q] ----
        {
            float lanep = 0.f;
            for (int q = 0; q < 6; ++q)
                lanep += (((lane >> q) & 1) ? 0.5f : -0.5f) * xr[q];
            for (int r = 0; r < REGS; ++r) {
                float ph = lanep;
                for (int q = 6; q < NQ; ++q)
                    ph += (((r >> (q - 6)) & 1) ? 0.5f : -0.5f) * xr[q];
                float s, c;
                __sincosf(ph, &s, &c);
                float nr = re[r] * c - im[r] * s;
                float ni = re[r] * s + im[r] * c;
                re[r] = nr; im[r] = ni;
            }
        }

        // ---- RY(ry[q]) on each qubit: [[c,-s],[s,c]], c=cos(t/2), s=sin(t/2) ----
        for (int q = 0; q < 6; ++q) {
            const int mask = 1 << q;
            const float h = 0.5f * ry[q];
            const float s = __sinf(h), c = __cosf(h);
            for (int r = 0; r < REGS; ++r) {
                float pr = __shfl_xor(re[r], mask, 64);
                float pi = __shfl_xor(im[r], mask, 64);
                if (lane & mask) { re[r] = s * pr + c * re[r]; im[r] = s * pi + c * im[r]; }
                else             { re[r] = c * re[r] - s * pr; im[r] = c * im[r] - s * pi; }
            }
        }
        for (int q = 6; q < NQ; ++q) {
            const int m = 1 << (q - 6);
            const float h = 0.5f * ry[q];
            const float s = __sinf(h), c = __cosf(h);
            for (int r = 0; r < REGS; ++r) {
                if (!(r & m)) {
                    const int r1 = r | m;
                    float a0r = re[r], a0i = im[r], a1r = re[r1], a1i = im[r1];
                    re[r]  = c * a0r - s * a1r;  im[r]  = c * a0i - s * a1i;
                    re[r1] = s * a0r + c * a1r;  im[r1] = s * a0i + c * a1i;
                }
            }
        }

        // ---- crz ring diagonal: phase = sum_n b_n * (b_{(n+1)%10} - 0.5) * rg[n] ----
        for (int r = 0; r < REGS; ++r) {
            const int idx = (r << 6) | lane;
            float ph = 0.f;
            for (int n = 0; n < NQ; ++n) {
                if ((idx >> n) & 1) {
                    const int bt = (idx >> ((n + 1) % NQ)) & 1;
                    ph += (bt ? 0.5f : -0.5f) * rg[n];
                }
            }
            float s, c;
            __sincosf(ph, &s, &c);
            float nr = re[r] * c - im[r] * s;
            float ni = re[r] * s + im[r] * c;
            re[r] = nr; im[r] = ni;
        }
    }

    // write psi_i (coalesced: lane-contiguous float2)
    float2* out = psi + i * DIM;
    for (int r = 0; r < REGS; ++r)
        out[(r << 6) | lane] = make_float2(re[r], im[r]);
}

// ---------------------------------------------------------------------------
// Kernel 2: K[p] = |<psi_j | psi_i>|^2 for pair p = i*64 + j. One wave/pair.
// ---------------------------------------------------------------------------
__global__ __launch_bounds__(64) void gram_kernel(
    const float2* __restrict__ psi,   // (64,1024)
    float* __restrict__ Kbuf)         // (4096,)
{
    const int p    = blockIdx.x;
    const int i    = p >> 6;
    const int j    = p & 63;
    const int lane = threadIdx.x;

    const float2* a = psi + i * DIM;
    const float2* b = psi + j * DIM;

    float zr = 0.f, zi = 0.f;   // <psi_j|psi_i> = sum conj(b)*a
    for (int r = 0; r < REGS; ++r) {
        const int k = (r << 6) | lane;
        float2 av = a[k], bv = b[k];
        zr += bv.x * av.x + bv.y * av.y;
        zi += bv.x * av.y - bv.y * av.x;
    }
    for (int off = 32; off; off >>= 1) {
        zr += __shfl_xor(zr, off, 64);
        zi += __shfl_xor(zi, off, 64);
    }
    if (lane == 0) Kbuf[p] = zr * zr + zi * zi;
}

// ---------------------------------------------------------------------------
// Kernel 3: KTA = sum(lm*K) / sqrt(sum(K*K) * sum(lm*lm)). One wave.
// ---------------------------------------------------------------------------
__global__ __launch_bounds__(64) void reduce_kernel(
    const float* __restrict__ Kbuf,
    const float* __restrict__ labels,
    float* __restrict__ out)
{
    const int lane = threadIdx.x;
    float slk = 0.f, skk = 0.f, sll = 0.f;
    for (int p = lane; p < NPTS * NPTS; p += 64) {
        const float K  = Kbuf[p];
        const float lm = labels[p >> 6] * labels[p & 63];
        slk += lm * K;
        skk += K * K;
        sll += lm * lm;
    }
    for (int off = 32; off; off >>= 1) {
        slk += __shfl_xor(slk, off, 64);
        skk += __shfl_xor(skk, off, 64);
        sll += __shfl_xor(sll, off, 64);
    }
    if (lane == 0) out[0] = slk / sqrtf(skk * sll);
}

extern "C" void kernel_launch(void* const* d_in, const int* in_sizes, int n_in,
                              void* d_out, int out_size, void* d_ws, size_t ws_size,
                              hipStream_t stream) {
    const float* data   = (const float*)d_in[0];  // (64,10)
    const float* labels = (const float*)d_in[1];  // (64,)
    const float* params = (const float*)d_in[2];  // (5,2,10)
    float* out = (float*)d_out;

    // workspace layout: psi (64*1024 float2 = 512 KB) | Kbuf (4096 floats)
    float2* psi  = (float2*)d_ws;
    float*  Kbuf = (float*)((char*)d_ws + (size_t)NPTS * DIM * sizeof(float2));

    state_kernel <<<NPTS,        64, 0, stream>>>(data, params, psi);
    gram_kernel  <<<NPTS * NPTS, 64, 0, stream>>>(psi, Kbuf);
    reduce_kernel<<<1,           64, 0, stream>>>(Kbuf, labels, out);
}

// Round 2
// 128.327 us; speedup vs baseline: 1.1157x; 1.1157x over previous
//
#include <hip/hip_runtime.h>
#include <math.h>

// Problem constants
#define NQ 10
#define DIM 1024          // 2^10
#define NPTS 64
#define DFEAT 10
#define NLAYERS 5
#define REGS 16           // DIM / 64 amplitudes per lane

// ---------------------------------------------------------------------------
// Kernel 1: simulate psi_i = U(x_i)|0> for each data point i (one wave/block).
// State layout: amplitude index idx = (r<<6) | lane, lane in [0,64), r in [0,16).
// Bits 0..5 of idx live in the lane index (cross-lane via shfl_xor);
// bits 6..9 live in the register index r (in-register butterflies).
// NOTE: all trig goes through native v_sin_f32/v_cos_f32 (__sinf/__cosf).
// __sincosf lowers to the PRECISE ocml sincos (~100 instr) — with only 64
// waves on the whole chip that serialized path was the R1 68 us.
// Phase magnitudes here are <= ~32 rad, well within native range.
// ---------------------------------------------------------------------------
__global__ __launch_bounds__(64) void state_kernel(
    const float* __restrict__ data,     // (64,10)
    const float* __restrict__ params,   // (5,2,10)
    float2* __restrict__ psi)           // (64,1024)
{
    const int i    = blockIdx.x;
    const int lane = threadIdx.x;

    // rz angle for qubit q is x[(start + 9 - q) % 10]; all starts are
    // multiples of 10, so theta_q = x[9-q] in every layer.
    float xr[NQ];
    {
        const float* x = data + i * DFEAT;
        for (int q = 0; q < NQ; ++q) xr[q] = x[9 - q];
    }

    float re[REGS], im[REGS];
    for (int r = 0; r < REGS; ++r) { re[r] = 0.f; im[r] = 0.f; }
    if (lane == 0) re[0] = 1.f;   // |0>

    const float is2 = 0.70710678118654752440f;

    for (int layer = 0; layer < NLAYERS; ++layer) {
        const float* ry = params + layer * 2 * NQ;       // bp[0]
        const float* rg = params + layer * 2 * NQ + NQ;  // bp[1]

        // ---- H on all qubits ----
        for (int q = 0; q < 6; ++q) {
            const int mask = 1 << q;
            for (int r = 0; r < REGS; ++r) {
                float pr = __shfl_xor(re[r], mask, 64);
                float pi = __shfl_xor(im[r], mask, 64);
                if (lane & mask) { re[r] = (pr - re[r]) * is2; im[r] = (pi - im[r]) * is2; }
                else             { re[r] = (re[r] + pr) * is2; im[r] = (im[r] + pi) * is2; }
            }
        }
        for (int q = 6; q < NQ; ++q) {
            const int m = 1 << (q - 6);
            for (int r = 0; r < REGS; ++r) {
                if (!(r & m)) {
                    const int r1 = r | m;
                    float a0r = re[r], a0i = im[r], a1r = re[r1], a1i = im[r1];
                    re[r]  = (a0r + a1r) * is2;  im[r]  = (a0i + a1i) * is2;
                    re[r1] = (a0r - a1r) * is2;  im[r1] = (a0i - a1i) * is2;
                }
            }
        }

        // ---- rz diagonal: phase = sum_q (b_q - 0.5) * xr[q] ----
        {
            float lanep = 0.f;
            for (int q = 0; q < 6; ++q)
                lanep += (((lane >> q) & 1) ? 0.5f : -0.5f) * xr[q];
            for (int r = 0; r < REGS; ++r) {
                float ph = lanep;
                for (int q = 6; q < NQ; ++q)
                    ph += (((r >> (q - 6)) & 1) ? 0.5f : -0.5f) * xr[q];
                float s = __sinf(ph), c = __cosf(ph);   // native v_sin/v_cos
                float nr = re[r] * c - im[r] * s;
                float ni = re[r] * s + im[r] * c;
                re[r] = nr; im[r] = ni;
            }
        }

        // ---- RY(ry[q]) on each qubit: [[c,-s],[s,c]], c=cos(t/2), s=sin(t/2) ----
        for (int q = 0; q < 6; ++q) {
            const int mask = 1 << q;
            const float h = 0.5f * ry[q];
            const float s = __sinf(h), c = __cosf(h);
            for (int r = 0; r < REGS; ++r) {
                float pr = __shfl_xor(re[r], mask, 64);
                float pi = __shfl_xor(im[r], mask, 64);
                if (lane & mask) { re[r] = s * pr + c * re[r]; im[r] = s * pi + c * im[r]; }
                else             { re[r] = c * re[r] - s * pr; im[r] = c * im[r] - s * pi; }
            }
        }
        for (int q = 6; q < NQ; ++q) {
            const int m = 1 << (q - 6);
            const float h = 0.5f * ry[q];
            const float s = __sinf(h), c = __cosf(h);
            for (int r = 0; r < REGS; ++r) {
                if (!(r & m)) {
                    const int r1 = r | m;
                    float a0r = re[r], a0i = im[r], a1r = re[r1], a1i = im[r1];
                    re[r]  = c * a0r - s * a1r;  im[r]  = c * a0i - s * a1i;
                    re[r1] = s * a0r + c * a1r;  im[r1] = s * a0i + c * a1i;
                }
            }
        }

        // ---- crz ring diagonal: phase = sum_n b_n * (b_{(n+1)%10} - 0.5) * rg[n] ----
        for (int r = 0; r < REGS; ++r) {
            const int idx = (r << 6) | lane;
            float ph = 0.f;
            for (int n = 0; n < NQ; ++n) {
                if ((idx >> n) & 1) {
                    const int bt = (idx >> ((n + 1) % NQ)) & 1;
                    ph += (bt ? 0.5f : -0.5f) * rg[n];
                }
            }
            float s = __sinf(ph), c = __cosf(ph);   // native v_sin/v_cos
            float nr = re[r] * c - im[r] * s;
            float ni = re[r] * s + im[r] * c;
            re[r] = nr; im[r] = ni;
        }
    }

    // write psi_i (coalesced: lane-contiguous float2)
    float2* out = psi + i * DIM;
    for (int r = 0; r < REGS; ++r)
        out[(r << 6) | lane] = make_float2(re[r], im[r]);
}

// ---------------------------------------------------------------------------
// Kernel 2: K[i][j] = |<psi_j | psi_i>|^2. K is symmetric -> compute only
// j >= i, write both entries. 256-thread blocks, one wave per pair.
// float4 loads = 2 complex amps per VMEM instruction.
// ---------------------------------------------------------------------------
__global__ __launch_bounds__(256) void gram_kernel(
    const float4* __restrict__ psi4,  // (64, 512) float4 view of psi
    float* __restrict__ Kbuf)         // (4096,)
{
    const int wave = threadIdx.x >> 6;
    const int lane = threadIdx.x & 63;
    const int p    = blockIdx.x * 4 + wave;   // 0..4095
    const int i    = p >> 6;
    const int j    = p & 63;
    if (j < i) return;                        // symmetry: partner wave writes us

    const float4* a = psi4 + i * (DIM / 2);
    const float4* b = psi4 + j * (DIM / 2);

    float zr = 0.f, zi = 0.f;   // <psi_j|psi_i> = sum conj(b)*a
#pragma unroll
    for (int r = 0; r < 8; ++r) {
        const int k = (r << 6) | lane;
        float4 av = a[k], bv = b[k];
        zr += bv.x * av.x + bv.y * av.y + bv.z * av.z + bv.w * av.w;
        zi += bv.x * av.y - bv.y * av.x + bv.z * av.w - bv.w * av.z;
    }
    for (int off = 32; off; off >>= 1) {
        zr += __shfl_xor(zr, off, 64);
        zi += __shfl_xor(zi, off, 64);
    }
    if (lane == 0) {
        const float k = zr * zr + zi * zi;
        Kbuf[p] = k;
        Kbuf[(j << 6) | i] = k;
    }
}

// ---------------------------------------------------------------------------
// Kernel 3: KTA = sum(lm*K) / sqrt(sum(K*K) * sum(lm*lm)). 4 waves + LDS.
// ---------------------------------------------------------------------------
__global__ __launch_bounds__(256) void reduce_kernel(
    const float* __restrict__ Kbuf,
    const float* __restrict__ labels,
    float* __restrict__ out)
{
    __shared__ float sm[3][4];
    const int tid  = threadIdx.x;
    const int lane = tid & 63;
    const int wave = tid >> 6;

    float slk = 0.f, skk = 0.f, sll = 0.f;
    for (int p = tid; p < NPTS * NPTS; p += 256) {
        const float K  = Kbuf[p];
        const float lm = labels[p >> 6] * labels[p & 63];
        slk += lm * K;
        skk += K * K;
        sll += lm * lm;
    }
    for (int off = 32; off; off >>= 1) {
        slk += __shfl_xor(slk, off, 64);
        skk += __shfl_xor(skk, off, 64);
        sll += __shfl_xor(sll, off, 64);
    }
    if (lane == 0) { sm[0][wave] = slk; sm[1][wave] = skk; sm[2][wave] = sll; }
    __syncthreads();
    if (tid == 0) {
        float a = sm[0][0] + sm[0][1] + sm[0][2] + sm[0][3];
        float b = sm[1][0] + sm[1][1] + sm[1][2] + sm[1][3];
        float c = sm[2][0] + sm[2][1] + sm[2][2] + sm[2][3];
        out[0] = a / sqrtf(b * c);
    }
}

extern "C" void kernel_launch(void* const* d_in, const int* in_sizes, int n_in,
                              void* d_out, int out_size, void* d_ws, size_t ws_size,
                              hipStream_t stream) {
    const float* data   = (const float*)d_in[0];  // (64,10)
    const float* labels = (const float*)d_in[1];  // (64,)
    const float* params = (const float*)d_in[2];  // (5,2,10)
    float* out = (float*)d_out;

    // workspace layout: psi (64*1024 float2 = 512 KB) | Kbuf (4096 floats)
    float2* psi  = (float2*)d_ws;
    float*  Kbuf = (float*)((char*)d_ws + (size_t)NPTS * DIM * sizeof(float2));

    state_kernel <<<NPTS,             64, 0, stream>>>(data, params, psi);
    gram_kernel  <<<NPTS * NPTS / 4, 256, 0, stream>>>((const float4*)psi, Kbuf);
    reduce_kernel<<<1,               256, 0, stream>>>(Kbuf, labels, out);
}

// Round 3
// 91.201 us; speedup vs baseline: 1.5699x; 1.4071x over previous
//
#include <hip/hip_runtime.h>
#include <math.h>

// Problem constants
#define NQ 10
#define DIM 1024          // 2^10
#define NPTS 64
#define DFEAT 10
#define NLAYERS 5
#define REGS 16           // DIM / 64 amplitudes per lane

// ---------------------------------------------------------------------------
// Kernel 1: simulate psi_i = U(x_i)|0> for each data point i (one wave/block).
// State layout: amplitude index idx = (r<<6) | lane.
// Bits 0..5 of idx live in the lane index (cross-lane via shfl_xor);
// bits 6..9 live in the register index r (in-register butterflies).
//
// R2 lesson: with 1 wave/CU every un-batched shuffle serializes at ~84 cyc
// (1920 shuffles ~= 162k cyc = the whole 67 us). All r-loops are now fully
// unrolled and each butterfly stage issues ALL 32 independent shuffles into
// temps before combining, so the DS latency is paid once per stage, not per
// shuffle.
// ---------------------------------------------------------------------------
__global__ __launch_bounds__(64) void state_kernel(
    const float* __restrict__ data,     // (64,10)
    const float* __restrict__ params,   // (5,2,10)
    float2* __restrict__ psi)           // (64,1024)
{
    const int i    = blockIdx.x;
    const int lane = threadIdx.x;

    // rz angle for qubit q is x[(start + 9 - q) % 10]; all starts are
    // multiples of 10, so theta_q = x[9-q] in every layer.
    float xr[NQ];
#pragma unroll
    for (int q = 0; q < NQ; ++q) xr[q] = data[i * DFEAT + (9 - q)];

    // rz phase is IDENTICAL every layer -> precompute sin/cos once.
    float rzs[REGS], rzc[REGS];
    {
        float lanep = 0.f;
#pragma unroll
        for (int q = 0; q < 6; ++q)
            lanep += (((lane >> q) & 1) ? 0.5f : -0.5f) * xr[q];
#pragma unroll
        for (int r = 0; r < REGS; ++r) {
            float ph = lanep;
#pragma unroll
            for (int q = 6; q < NQ; ++q)
                ph += (((r >> (q - 6)) & 1) ? 0.5f : -0.5f) * xr[q];
            rzs[r] = __sinf(ph);
            rzc[r] = __cosf(ph);
        }
    }

    float re[REGS], im[REGS];
#pragma unroll
    for (int r = 0; r < REGS; ++r) { re[r] = 0.f; im[r] = 0.f; }
    if (lane == 0) re[0] = 1.f;   // |0>

    const float is2 = 0.70710678118654752440f;

    for (int layer = 0; layer < NLAYERS; ++layer) {
        const float* ry = params + layer * 2 * NQ;       // bp[0]
        const float* rg = params + layer * 2 * NQ + NQ;  // bp[1]

        // ---- H on all qubits ----
        // lane bits: batched butterfly per stage
        for (int q = 0; q < 6; ++q) {
            const int mask = 1 << q;
            float pr[REGS], pi[REGS];
#pragma unroll
            for (int r = 0; r < REGS; ++r) {
                pr[r] = __shfl_xor(re[r], mask, 64);
                pi[r] = __shfl_xor(im[r], mask, 64);
            }
            const bool hi = (lane & mask) != 0;
#pragma unroll
            for (int r = 0; r < REGS; ++r) {
                re[r] = hi ? (pr[r] - re[r]) * is2 : (re[r] + pr[r]) * is2;
                im[r] = hi ? (pi[r] - im[r]) * is2 : (im[r] + pi[r]) * is2;
            }
        }
        // reg bits: pure VALU
#pragma unroll
        for (int q = 6; q < NQ; ++q) {
            const int m = 1 << (q - 6);
#pragma unroll
            for (int r = 0; r < REGS; ++r) {
                if (!(r & m)) {
                    const int r1 = r | m;
                    float a0r = re[r], a0i = im[r], a1r = re[r1], a1i = im[r1];
                    re[r]  = (a0r + a1r) * is2;  im[r]  = (a0i + a1i) * is2;
                    re[r1] = (a0r - a1r) * is2;  im[r1] = (a0i - a1i) * is2;
                }
            }
        }

        // ---- rz diagonal (precomputed sin/cos) ----
#pragma unroll
        for (int r = 0; r < REGS; ++r) {
            float s = rzs[r], c = rzc[r];
            float nr = re[r] * c - im[r] * s;
            float ni = re[r] * s + im[r] * c;
            re[r] = nr; im[r] = ni;
        }

        // ---- RY(ry[q]): [[c,-s],[s,c]], c=cos(t/2), s=sin(t/2) ----
        for (int q = 0; q < 6; ++q) {
            const int mask = 1 << q;
            const float h = 0.5f * ry[q];
            const float s = __sinf(h), c = __cosf(h);
            float pr[REGS], pi[REGS];
#pragma unroll
            for (int r = 0; r < REGS; ++r) {
                pr[r] = __shfl_xor(re[r], mask, 64);
                pi[r] = __shfl_xor(im[r], mask, 64);
            }
            const bool hi = (lane & mask) != 0;
#pragma unroll
            for (int r = 0; r < REGS; ++r) {
                re[r] = hi ? s * pr[r] + c * re[r] : c * re[r] - s * pr[r];
                im[r] = hi ? s * pi[r] + c * im[r] : c * im[r] - s * pi[r];
            }
        }
#pragma unroll
        for (int q = 6; q < NQ; ++q) {
            const int m = 1 << (q - 6);
            const float h = 0.5f * ry[q];
            const float s = __sinf(h), c = __cosf(h);
#pragma unroll
            for (int r = 0; r < REGS; ++r) {
                if (!(r & m)) {
                    const int r1 = r | m;
                    float a0r = re[r], a0i = im[r], a1r = re[r1], a1i = im[r1];
                    re[r]  = c * a0r - s * a1r;  im[r]  = c * a0i - s * a1i;
                    re[r1] = s * a0r + c * a1r;  im[r1] = s * a0i + c * a1i;
                }
            }
        }

        // ---- crz ring diagonal: phase = sum_n b_n * (b_{(n+1)%10} - 0.5) * rg[n] ----
#pragma unroll
        for (int r = 0; r < REGS; ++r) {
            const int idx = (r << 6) | lane;
            float ph = 0.f;
#pragma unroll
            for (int n = 0; n < NQ; ++n) {
                const int bc = (idx >> n) & 1;
                const int bt = (idx >> ((n + 1) % NQ)) & 1;
                float t = bc ? (bt ? 0.5f : -0.5f) : 0.f;
                ph += t * rg[n];
            }
            float s = __sinf(ph), c = __cosf(ph);
            float nr = re[r] * c - im[r] * s;
            float ni = re[r] * s + im[r] * c;
            re[r] = nr; im[r] = ni;
        }
    }

    // write psi_i (coalesced: lane-contiguous float2)
    float2* out = psi + i * DIM;
#pragma unroll
    for (int r = 0; r < REGS; ++r)
        out[(r << 6) | lane] = make_float2(re[r], im[r]);
}

// ---------------------------------------------------------------------------
// Kernel 2: K[i][j] = |<psi_j | psi_i>|^2. Symmetric -> compute j >= i, write
// both. 256-thread blocks, one wave per pair. float4 loads.
// ---------------------------------------------------------------------------
__global__ __launch_bounds__(256) void gram_kernel(
    const float4* __restrict__ psi4,  // (64, 512) float4 view of psi
    float* __restrict__ Kbuf)         // (4096,)
{
    const int wave = threadIdx.x >> 6;
    const int lane = threadIdx.x & 63;
    const int p    = blockIdx.x * 4 + wave;   // 0..4095
    const int i    = p >> 6;
    const int j    = p & 63;
    if (j < i) return;                        // symmetry: partner wave writes us

    const float4* a = psi4 + i * (DIM / 2);
    const float4* b = psi4 + j * (DIM / 2);

    float zr = 0.f, zi = 0.f;   // <psi_j|psi_i> = sum conj(b)*a
#pragma unroll
    for (int r = 0; r < 8; ++r) {
        const int k = (r << 6) | lane;
        float4 av = a[k], bv = b[k];
        zr += bv.x * av.x + bv.y * av.y + bv.z * av.z + bv.w * av.w;
        zi += bv.x * av.y - bv.y * av.x + bv.z * av.w - bv.w * av.z;
    }
#pragma unroll
    for (int off = 32; off; off >>= 1) {
        zr += __shfl_xor(zr, off, 64);
        zi += __shfl_xor(zi, off, 64);
    }
    if (lane == 0) {
        const float k = zr * zr + zi * zi;
        Kbuf[p] = k;
        Kbuf[(j << 6) | i] = k;
    }
}

// ---------------------------------------------------------------------------
// Kernel 3: KTA = sum(lm*K) / sqrt(sum(K*K) * sum(lm*lm)). 4 waves + LDS.
// ---------------------------------------------------------------------------
__global__ __launch_bounds__(256) void reduce_kernel(
    const float* __restrict__ Kbuf,
    const float* __restrict__ labels,
    float* __restrict__ out)
{
    __shared__ float sm[3][4];
    const int tid  = threadIdx.x;
    const int lane = tid & 63;
    const int wave = tid >> 6;

    float slk = 0.f, skk = 0.f, sll = 0.f;
#pragma unroll
    for (int it = 0; it < (NPTS * NPTS) / 256; ++it) {
        const int p = it * 256 + tid;
        const float K  = Kbuf[p];
        const float lm = labels[p >> 6] * labels[p & 63];
        slk += lm * K;
        skk += K * K;
        sll += lm * lm;
    }
#pragma unroll
    for (int off = 32; off; off >>= 1) {
        slk += __shfl_xor(slk, off, 64);
        skk += __shfl_xor(skk, off, 64);
        sll += __shfl_xor(sll, off, 64);
    }
    if (lane == 0) { sm[0][wave] = slk; sm[1][wave] = skk; sm[2][wave] = sll; }
    __syncthreads();
    if (tid == 0) {
        float a = sm[0][0] + sm[0][1] + sm[0][2] + sm[0][3];
        float b = sm[1][0] + sm[1][1] + sm[1][2] + sm[1][3];
        float c = sm[2][0] + sm[2][1] + sm[2][2] + sm[2][3];
        out[0] = a / sqrtf(b * c);
    }
}

extern "C" void kernel_launch(void* const* d_in, const int* in_sizes, int n_in,
                              void* d_out, int out_size, void* d_ws, size_t ws_size,
                              hipStream_t stream) {
    const float* data   = (const float*)d_in[0];  // (64,10)
    const float* labels = (const float*)d_in[1];  // (64,)
    const float* params = (const float*)d_in[2];  // (5,2,10)
    float* out = (float*)d_out;

    // workspace layout: psi (64*1024 float2 = 512 KB) | Kbuf (4096 floats)
    float2* psi  = (float2*)d_ws;
    float*  Kbuf = (float*)((char*)d_ws + (size_t)NPTS * DIM * sizeof(float2));

    state_kernel <<<NPTS,             64, 0, stream>>>(data, params, psi);
    gram_kernel  <<<NPTS * NPTS / 4, 256, 0, stream>>>((const float4*)psi, Kbuf);
    reduce_kernel<<<1,               256, 0, stream>>>(Kbuf, labels, out);
}